// Round 8
// baseline (227.764 us; speedup 1.0000x reference)
//
#include <hip/hip_runtime.h>
#include <hip/hip_bf16.h>
#include <cstdint>
#include <cstddef>

// LearnableUpsampler: quant -> convT(K=4,s=2) -> quant -> conv7+silu -> quant -> conv7 + res -> LN
// Round 18: epilogue fusion. Conv blocks own ALL 512 channels for 32 tokens (8 waves x
// 32M x 64N, grid 256 = 1 block/CU, 2 waves/SIMD) so each conv absorbs its consumer:
//   convT    -> writes h f32 + per-token quant (qh, invh)        [was: +act_quant launch]
//   conv7#1  -> silu + quant (qh2, invh2), NO f32 r buffer       [was: +16.8MB w + act_quant]
//   conv7#2  -> +residual + in-epilogue deterministic LayerNorm  [was: +ln launch]
// 11 -> 8 dispatches, -60MB HBM round-trips. All reductions fixed-order (replay-deterministic).
// Conv main loop keeps the R3/R7-proven barrier-free stream (A staged once in LDS, B per-lane
// global->reg, linear stride); R7's abssum two-stage deterministic reduction retained.

#define B_ 2
#define T_ 2048
#define L_ 4096
#define C_ 512

static constexpr int NUP = 512 * 512 * 4;
static constexpr int NR  = 512 * 512 * 7;

using v4i  = __attribute__((ext_vector_type(4))) int;
using v16i = __attribute__((ext_vector_type(16))) int;

__device__ __forceinline__ void gl16(const void* g, void* l) {
  __builtin_amdgcn_global_load_lds((const __attribute__((address_space(1))) unsigned int*)g,
                                   (__attribute__((address_space(3))) unsigned int*)l,
                                   16, 0, 0);
}

// ---------------- reductions ----------------

__device__ inline float block_reduce_sum_256(float v) {
  #pragma unroll
  for (int off = 32; off > 0; off >>= 1) v += __shfl_down(v, off, 64);
  __shared__ float s[4];
  __syncthreads();
  if ((threadIdx.x & 63) == 0) s[threadIdx.x >> 6] = v;
  __syncthreads();
  return (s[0] + s[1]) + (s[2] + s[3]);
}

// stage 1: fixed-slot partial sums (deterministic: no atomics)
__global__ void abssum3_partial(const float* __restrict__ w0, const float* __restrict__ w1,
                                const float* __restrict__ w2, float* __restrict__ partial) {
  int y = blockIdx.y;
  const float* w = (y == 0) ? w0 : (y == 1) ? w1 : w2;
  int n = (y == 0) ? NUP : NR;
  int idx = blockIdx.x * 256 + threadIdx.x;
  float s = 0.f;
  for (int i = idx; i < n; i += gridDim.x * 256) s += fabsf(w[i]);
  s = block_reduce_sum_256(s);
  if (threadIdx.x == 0) partial[y * 256 + blockIdx.x] = s;
}

// stage 2: fixed-order tree over the 256 partials (deterministic)
__global__ void abssum3_final(const float* __restrict__ partial, float* __restrict__ out) {
  int y = blockIdx.x;
  float v = partial[y * 256 + threadIdx.x];
  v = block_reduce_sum_256(v);
  if (threadIdx.x == 0) out[y] = v;
}

// ---------------- ternarize + repack, one launch; layout [tap][kq32][co512][16] ----------------
__global__ void tern_all_kernel(const float* __restrict__ wu, const float* __restrict__ w1,
                                const float* __restrict__ w2, int8_t* __restrict__ ou,
                                int8_t* __restrict__ o1, int8_t* __restrict__ o2,
                                const float* __restrict__ wsum) {
  int y = blockIdx.y;
  int idx = blockIdx.x * 256 + threadIdx.x;
  if (y == 0) {
    if (idx >= NUP) return;
    float mean = wsum[0] * (1.0f / (float)NUP);
    float scale = 1.0f / fmaxf(mean, 1e-5f);
    float t = rintf(wu[idx] * scale);
    t = fminf(fmaxf(t, -1.f), 1.f);
    int ci = idx >> 11;
    int co = (idx >> 2) & 511;
    int k = idx & 3;
    // ptap order: parity0 {k=3,k=1}, parity1 {k=2,k=0}
    int ptap = (k == 3) ? 0 : (k == 1) ? 1 : (k == 2) ? 2 : 3;
    ou[(((size_t)ptap * 32 + (ci >> 4)) * 512 + co) * 16 + (ci & 15)] = (int8_t)t;
  } else {
    if (idx >= NR) return;
    const float* w = (y == 1) ? w1 : w2;
    int8_t* o = (y == 1) ? o1 : o2;
    float mean = wsum[y] * (1.0f / (float)NR);
    float scale = 1.0f / fmaxf(mean, 1e-5f);
    float t = rintf(w[idx] * scale);
    t = fminf(fmaxf(t, -1.f), 1.f);
    int co = idx / 3584;
    int rem = idx - co * 3584;
    int ci = rem / 7;
    int k = rem - ci * 7;
    o[(((size_t)k * 32 + (ci >> 4)) * 512 + co) * 16 + (ci & 15)] = (int8_t)t;
  }
}

// ---------------- per-token activation quant for x; packed q layout [b][kq32][LinH][16] ----------------
__global__ void act_quant_kernel(const float* __restrict__ x, int8_t* __restrict__ qd,
                                 float* __restrict__ inv, int Lb, int lbsh, int LinH) {
  int tok = blockIdx.x;
  int b = tok >> lbsh;
  int t = tok & (Lb - 1);
  const float* row = x + (size_t)tok * C_;
  int tid = threadIdx.x;
  float v0 = row[tid];
  float v1 = row[tid + 256];
  float m = fmaxf(fabsf(v0), fabsf(v1));
  #pragma unroll
  for (int off = 32; off > 0; off >>= 1) m = fmaxf(m, __shfl_down(m, off, 64));
  __shared__ float s[4];
  __shared__ __align__(16) int8_t sq[512];
  if ((tid & 63) == 0) s[tid >> 6] = m;
  __syncthreads();
  m = fmaxf(fmaxf(s[0], s[1]), fmaxf(s[2], s[3]));
  float scale = 127.0f / fmaxf(m, 1e-5f);
  float q0 = fminf(fmaxf(rintf(v0 * scale), -128.f), 127.f);
  float q1 = fminf(fmaxf(rintf(v1 * scale), -128.f), 127.f);
  sq[tid] = (int8_t)q0;
  sq[tid + 256] = (int8_t)q1;
  __syncthreads();
  if (tid < 32)
    *(v4i*)(qd + ((size_t)(b * 32 + tid) * LinH + 8 + t) * 16) = *(const v4i*)(sq + tid * 16);
  if (tid == 0) inv[(size_t)b * LinH + 8 + t] = 1.0f / scale;
}

// ---------------- fused MFMA conv ----------------
// Block 512 thr (8 waves). Block tile 32M x 512N (ALL channels); wave w owns cols
// [w*64, w*64+64): acc0 (cols +0..31), acc1 (cols +32..63). A staged once in LDS.
// EPI: 0 = write h f32 + quant(qout,invout)   (convT)
//      1 = silu + quant(qout,invout), no f32   (conv7#1)
//      2 = +res, deterministic LayerNorm -> lnout (conv7#2)
template<int NTAPS, bool CONVT, int EPI>
__global__ __launch_bounds__(512, 2)
void conv_fused(const int8_t* __restrict__ qin, const float* __restrict__ invp, int LinH,
                const int8_t* __restrict__ wq, const float* __restrict__ wsum, int widx,
                float wninv, const float* __restrict__ bias,
                float* __restrict__ hout,
                int8_t* __restrict__ qout, float* __restrict__ invout, int LoutH,
                const float* __restrict__ res, const float* __restrict__ g,
                const float* __restrict__ be, float* __restrict__ lnout, int Lout) {
  __shared__ __align__(16) int8_t sA[32 * 38 * 16];      // 19456 B
  __shared__ float sInv[40];
  __shared__ float sRedA[8][32];
  __shared__ float sRedB[8][32];
  __shared__ float sS0[32];
  __shared__ float sS1[32];
  __shared__ __align__(16) int8_t sQ[32][512];           // EPI 0/1 only (DCE'd for EPI2)

  const int tid = threadIdx.x;
  const int w = tid >> 6, lane = tid & 63, q = lane >> 5, l31 = lane & 31;
  const int t0 = blockIdx.x * 32;
  const int b = blockIdx.y;
  int s0 = -3;
  const int8_t* wq_p = wq;
  int parity = 0;
  if (CONVT) {
    parity = blockIdx.z;
    s0 = parity - 1;
    wq_p += (size_t)parity * 2 * 32 * 512 * 16;
  }
  const int8_t* qin_b = qin + (size_t)b * 32 * LinH * 16;
  const float* inv_b = invp + (size_t)b * LinH + 8;

  // ---- prologue: stage A (32 kq x 38 rows = 1216 16B units) + sInv, one barrier
  #pragma unroll
  for (int i = 0; i < 3; ++i) {
    int base = i * 512 + w * 64;       // wave-uniform
    if (base < 1216) {
      int u = base + lane;
      int kq = u / 38;
      int row = u - kq * 38;
      gl16(qin_b + ((size_t)kq * LinH + (size_t)(t0 + 5 + row)) * 16,
           sA + (size_t)base * 16);
    }
  }
  if (tid < 38) sInv[tid] = inv_b[t0 - 3 + tid];
  __syncthreads();   // drains gl16 (vmcnt) + sInv write; the ONLY main-path barrier

  float fs0[16], fs1[16];
  v16i acc0{}, acc1{};
  #pragma unroll
  for (int r = 0; r < 16; ++r) { fs0[r] = 0.f; fs1[r] = 0.f; acc0[r] = 0; acc1[r] = 0; }

  const int col0 = w * 64 + l31;
  const int8_t* wt_base = wq_p + ((size_t)q * 512 + (size_t)col0) * 16;

  #pragma unroll 1
  for (int tap = 0; tap < NTAPS; ++tap) {
    const int shift = s0 + tap;
    const int8_t* aP = sA + (((size_t)q * 38) + (size_t)(3 + shift + l31)) * 16;
    const int8_t* wt = wt_base + (size_t)tap * (32 * 512 * 16);
    #pragma unroll
    for (int ks = 0; ks < 16; ++ks) {
      v4i a  = *(const v4i*)(aP + (size_t)ks * (2 * 38 * 16));
      v4i b0 = *(const v4i*)(wt + (size_t)ks * 16384);
      v4i b1 = *(const v4i*)(wt + (size_t)ks * 16384 + 512);
      acc0 = __builtin_amdgcn_mfma_i32_32x32x32_i8(a, b0, acc0, 0, 0, 0);
      acc1 = __builtin_amdgcn_mfma_i32_32x32x32_i8(a, b1, acc1, 0, 0, 0);
    }
    // end of tap: fold i32 -> fp32 with per-input-row scale (same row for both col halves)
    #pragma unroll
    for (int r = 0; r < 16; ++r) {
      int ro = (r & 3) + 8 * (r >> 2) + 4 * q;
      float sc = sInv[3 + shift + ro];
      fs0[r] = fmaf((float)acc0[r], sc, fs0[r]);
      fs1[r] = fmaf((float)acc1[r], sc, fs1[r]);
      acc0[r] = 0; acc1[r] = 0;
    }
  }

  // ---- epilogue: bias/dequant, then fused consumer stage
  const float wdq = fmaxf(wsum[widx] * wninv, 1e-5f);
  const float bv0 = bias[col0], bv1 = bias[col0 + 32];
  #pragma unroll
  for (int r = 0; r < 16; ++r) {
    fs0[r] = fs0[r] * wdq + bv0;
    fs1[r] = fs1[r] * wdq + bv1;
  }

  if constexpr (EPI == 0) {
    // write h f32 (token = 2*(t0+ro)+parity)
    #pragma unroll
    for (int r = 0; r < 16; ++r) {
      int ro = (r & 3) + 8 * (r >> 2) + 4 * q;
      size_t base = ((size_t)b * Lout + 2 * (size_t)(t0 + ro) + parity) * 512;
      hout[base + col0] = fs0[r];
      hout[base + col0 + 32] = fs1[r];
    }
  }
  if constexpr (EPI == 1) {
    #pragma unroll
    for (int r = 0; r < 16; ++r) {
      fs0[r] = fs0[r] / (1.0f + expf(-fs0[r]));
      fs1[r] = fs1[r] / (1.0f + expf(-fs1[r]));
    }
  }

  if constexpr (EPI <= 1) {
    // ---- per-token absmax (deterministic: shuffle tree + fixed 8-wave fold)
    #pragma unroll
    for (int r = 0; r < 16; ++r) {
      int ro = (r & 3) + 8 * (r >> 2) + 4 * q;
      float m = fmaxf(fabsf(fs0[r]), fabsf(fs1[r]));
      #pragma unroll
      for (int off = 16; off > 0; off >>= 1) m = fmaxf(m, __shfl_xor(m, off, 64));
      if (l31 == 0) sRedA[w][ro] = m;
    }
    __syncthreads();
    if (tid < 32) {
      float m = sRedA[0][tid];
      #pragma unroll
      for (int ww = 1; ww < 8; ++ww) m = fmaxf(m, sRedA[ww][tid]);
      float mm = fmaxf(m, 1e-5f);
      sS0[tid] = 127.0f / mm;
      int tok = CONVT ? (2 * (t0 + tid) + parity) : (t0 + tid);
      invout[(size_t)b * LoutH + 8 + tok] = mm * (1.0f / 127.0f);
    }
    __syncthreads();
    #pragma unroll
    for (int r = 0; r < 16; ++r) {
      int ro = (r & 3) + 8 * (r >> 2) + 4 * q;
      float sc = sS0[ro];
      float q0 = fminf(fmaxf(rintf(fs0[r] * sc), -128.f), 127.f);
      float q1 = fminf(fmaxf(rintf(fs1[r] * sc), -128.f), 127.f);
      sQ[ro][col0] = (int8_t)q0;
      sQ[ro][col0 + 32] = (int8_t)q1;
    }
    __syncthreads();
    #pragma unroll
    for (int it = 0; it < 2; ++it) {
      int u = it * 512 + tid;          // 0..1023: (row, 16B-unit)
      int row = u >> 5, unit = u & 31;
      int tok = CONVT ? (2 * (t0 + row) + parity) : (t0 + row);
      *(v4i*)(qout + (((size_t)b * 32 + unit) * LoutH + 8 + tok) * 16) =
          *(const v4i*)(&sQ[row][unit * 16]);
    }
  } else {
    // ---- EPI 2: residual + deterministic two-pass LayerNorm
    #pragma unroll
    for (int r = 0; r < 16; ++r) {
      int ro = (r & 3) + 8 * (r >> 2) + 4 * q;
      size_t base = ((size_t)b * Lout + (size_t)(t0 + ro)) * 512;
      fs0[r] += res[base + col0];
      fs1[r] += res[base + col0 + 32];
    }
    // pass 1: mean
    #pragma unroll
    for (int r = 0; r < 16; ++r) {
      int ro = (r & 3) + 8 * (r >> 2) + 4 * q;
      float s = fs0[r] + fs1[r];
      #pragma unroll
      for (int off = 16; off > 0; off >>= 1) s += __shfl_xor(s, off, 64);
      if (l31 == 0) sRedA[w][ro] = s;
    }
    __syncthreads();
    if (tid < 32) {
      float s = sRedA[0][tid];
      #pragma unroll
      for (int ww = 1; ww < 8; ++ww) s += sRedA[ww][tid];
      sS0[tid] = s * (1.0f / 512.0f);
    }
    __syncthreads();
    // pass 2: variance around mean
    #pragma unroll
    for (int r = 0; r < 16; ++r) {
      int ro = (r & 3) + 8 * (r >> 2) + 4 * q;
      float mu = sS0[ro];
      float d0 = fs0[r] - mu, d1 = fs1[r] - mu;
      float ss = d0 * d0 + d1 * d1;
      #pragma unroll
      for (int off = 16; off > 0; off >>= 1) ss += __shfl_xor(ss, off, 64);
      if (l31 == 0) sRedB[w][ro] = ss;
    }
    __syncthreads();
    if (tid < 32) {
      float ssum = sRedB[0][tid];
      #pragma unroll
      for (int ww = 1; ww < 8; ++ww) ssum += sRedB[ww][tid];
      float var = ssum * (1.0f / 512.0f);
      sS1[tid] = 1.0f / sqrtf(var + 1e-5f);
    }
    __syncthreads();
    const float g0 = g[col0], g1 = g[col0 + 32];
    const float e0 = be[col0], e1 = be[col0 + 32];
    #pragma unroll
    for (int r = 0; r < 16; ++r) {
      int ro = (r & 3) + 8 * (r >> 2) + 4 * q;
      float mu = sS0[ro], rs = sS1[ro];
      size_t base = ((size_t)b * Lout + (size_t)(t0 + ro)) * 512;
      lnout[base + col0]      = (fs0[r] - mu) * rs * g0 + e0;
      lnout[base + col0 + 32] = (fs1[r] - mu) * rs * g1 + e1;
    }
  }
}

// ---------------- launch ----------------

extern "C" void kernel_launch(void* const* d_in, const int* in_sizes, int n_in,
                              void* d_out, int out_size, void* d_ws, size_t ws_size,
                              hipStream_t stream) {
  const float* x    = (const float*)d_in[0];
  const float* w_up = (const float*)d_in[1];
  const float* b_up = (const float*)d_in[2];
  const float* w_r1 = (const float*)d_in[3];
  const float* b_r1 = (const float*)d_in[4];
  const float* w_r2 = (const float*)d_in[5];
  const float* b_r2 = (const float*)d_in[6];
  const float* ln_w = (const float*)d_in[7];
  const float* ln_b = (const float*)d_in[8];
  float* out = (float*)d_out;

  const int LXH = T_ + 16;   // 2064 rows per batch (halo 8 each side)
  const int LHH = L_ + 16;   // 4112

  char* ws = (char*)d_ws;
  size_t off = 0;
  auto alloc = [&](size_t sz) { size_t p = off; off += (sz + 255) & ~(size_t)255; return p; };
  // zero region: wsum + q buffers + inv buffers (halo rows/scales must be 0)
  float*  wsum  = (float*) (ws + alloc(256));
  int8_t* qx    = (int8_t*)(ws + alloc((size_t)B_ * 32 * LXH * 16));   // 2.1 MB
  int8_t* qh    = (int8_t*)(ws + alloc((size_t)B_ * 32 * LHH * 16));   // 4.2 MB
  int8_t* qh2   = (int8_t*)(ws + alloc((size_t)B_ * 32 * LHH * 16));   // 4.2 MB
  float*  invx  = (float*) (ws + alloc((size_t)B_ * LXH * 4));
  float*  invh  = (float*) (ws + alloc((size_t)B_ * LHH * 4));
  float*  invh2 = (float*) (ws + alloc((size_t)B_ * LHH * 4));
  size_t zero_bytes = off;
  float*  partial = (float*)(ws + alloc(3 * 256 * 4));                 // det. reduction slots
  int8_t* wqup = (int8_t*)(ws + alloc((size_t)4 * 32 * 512 * 16));     // 1 MB
  int8_t* wq1  = (int8_t*)(ws + alloc((size_t)7 * 32 * 512 * 16));     // 1.8 MB
  int8_t* wq2  = (int8_t*)(ws + alloc((size_t)7 * 32 * 512 * 16));     // 1.8 MB
  float*  h    = (float*) (ws + alloc((size_t)B_ * L_ * C_ * 4));      // 16.8 MB

  hipMemsetAsync(ws, 0, zero_bytes, stream);  // wsum + q/inv halos

  abssum3_partial<<<dim3(256, 3), 256, 0, stream>>>(w_up, w_r1, w_r2, partial);
  abssum3_final<<<3, 256, 0, stream>>>(partial, wsum);
  tern_all_kernel<<<dim3(NR / 256, 3), 256, 0, stream>>>(w_up, w_r1, w_r2,
                                                         wqup, wq1, wq2, wsum);

  act_quant_kernel<<<B_ * T_, 256, 0, stream>>>(x, qx, invx, T_, 11, LXH);

  // convT + fused quant: grid (64 mtiles, B, parity) = 256 blocks
  conv_fused<2, true, 0><<<dim3(64, B_, 2), 512, 0, stream>>>(
      qx, invx, LXH, wqup, wsum, 0, 1.0f / (float)NUP, b_up,
      h, qh, invh, LHH, nullptr, nullptr, nullptr, nullptr, L_);

  // conv7#1 + silu + fused quant (no f32 r buffer): grid (128, B) = 256 blocks
  conv_fused<7, false, 1><<<dim3(128, B_, 1), 512, 0, stream>>>(
      qh, invh, LHH, wq1, wsum, 1, 1.0f / (float)NR, b_r1,
      nullptr, qh2, invh2, LHH, nullptr, nullptr, nullptr, nullptr, L_);

  // conv7#2 + residual + fused LayerNorm -> out: grid (128, B) = 256 blocks
  conv_fused<7, false, 2><<<dim3(128, B_, 1), 512, 0, stream>>>(
      qh2, invh2, LHH, wq2, wsum, 2, 1.0f / (float)NR, b_r2,
      nullptr, nullptr, nullptr, 0, h, ln_w, ln_b, out, L_);
}

// Round 9
// 206.086 us; speedup vs baseline: 1.1052x; 1.1052x over previous
//
#include <hip/hip_runtime.h>
#include <hip/hip_bf16.h>
#include <cstdint>
#include <cstddef>

// LearnableUpsampler: quant -> convT(K=4,s=2) -> quant -> conv7+silu -> quant -> conv7 + res -> LN
// Round 19: R8 fusion + coverage restored. Empirical model from R2/R3/R4/R8: conv time tracks
// (waves/SIMD) x (MFMAs per B-load). R8's 8-wave block = product 2 -> 51us. This round:
// 1024 thr = 16 waves, wave tile 32M x 32N (1 acc + 1 fs = 32 VGPR state, no spill), block
// still token-complete 32M x 512N (needed for fused per-token quant/LN reductions), grid 256
// = 1 block/CU = 4 waves/SIMD -> product 4 (the measured-best regime, ~32us conv7).
// Fusion kept: convT->quant, conv7#1->silu+quant (no f32 r buffer), conv7#2->res+LN.
// All reductions fixed-order (replay-deterministic); R7 abssum two-stage reduction retained.

#define B_ 2
#define T_ 2048
#define L_ 4096
#define C_ 512

static constexpr int NUP = 512 * 512 * 4;
static constexpr int NR  = 512 * 512 * 7;

using v4i  = __attribute__((ext_vector_type(4))) int;
using v16i = __attribute__((ext_vector_type(16))) int;

__device__ __forceinline__ void gl16(const void* g, void* l) {
  __builtin_amdgcn_global_load_lds((const __attribute__((address_space(1))) unsigned int*)g,
                                   (__attribute__((address_space(3))) unsigned int*)l,
                                   16, 0, 0);
}

// ---------------- reductions ----------------

__device__ inline float block_reduce_sum_256(float v) {
  #pragma unroll
  for (int off = 32; off > 0; off >>= 1) v += __shfl_down(v, off, 64);
  __shared__ float s[4];
  __syncthreads();
  if ((threadIdx.x & 63) == 0) s[threadIdx.x >> 6] = v;
  __syncthreads();
  return (s[0] + s[1]) + (s[2] + s[3]);
}

// stage 1: fixed-slot partial sums (deterministic: no atomics)
__global__ void abssum3_partial(const float* __restrict__ w0, const float* __restrict__ w1,
                                const float* __restrict__ w2, float* __restrict__ partial) {
  int y = blockIdx.y;
  const float* w = (y == 0) ? w0 : (y == 1) ? w1 : w2;
  int n = (y == 0) ? NUP : NR;
  int idx = blockIdx.x * 256 + threadIdx.x;
  float s = 0.f;
  for (int i = idx; i < n; i += gridDim.x * 256) s += fabsf(w[i]);
  s = block_reduce_sum_256(s);
  if (threadIdx.x == 0) partial[y * 256 + blockIdx.x] = s;
}

// stage 2: fixed-order tree over the 256 partials (deterministic)
__global__ void abssum3_final(const float* __restrict__ partial, float* __restrict__ out) {
  int y = blockIdx.x;
  float v = partial[y * 256 + threadIdx.x];
  v = block_reduce_sum_256(v);
  if (threadIdx.x == 0) out[y] = v;
}

// ---------------- ternarize + repack, one launch; layout [tap][kq32][co512][16] ----------------
__global__ void tern_all_kernel(const float* __restrict__ wu, const float* __restrict__ w1,
                                const float* __restrict__ w2, int8_t* __restrict__ ou,
                                int8_t* __restrict__ o1, int8_t* __restrict__ o2,
                                const float* __restrict__ wsum) {
  int y = blockIdx.y;
  int idx = blockIdx.x * 256 + threadIdx.x;
  if (y == 0) {
    if (idx >= NUP) return;
    float mean = wsum[0] * (1.0f / (float)NUP);
    float scale = 1.0f / fmaxf(mean, 1e-5f);
    float t = rintf(wu[idx] * scale);
    t = fminf(fmaxf(t, -1.f), 1.f);
    int ci = idx >> 11;
    int co = (idx >> 2) & 511;
    int k = idx & 3;
    // ptap order: parity0 {k=3,k=1}, parity1 {k=2,k=0}
    int ptap = (k == 3) ? 0 : (k == 1) ? 1 : (k == 2) ? 2 : 3;
    ou[(((size_t)ptap * 32 + (ci >> 4)) * 512 + co) * 16 + (ci & 15)] = (int8_t)t;
  } else {
    if (idx >= NR) return;
    const float* w = (y == 1) ? w1 : w2;
    int8_t* o = (y == 1) ? o1 : o2;
    float mean = wsum[y] * (1.0f / (float)NR);
    float scale = 1.0f / fmaxf(mean, 1e-5f);
    float t = rintf(w[idx] * scale);
    t = fminf(fmaxf(t, -1.f), 1.f);
    int co = idx / 3584;
    int rem = idx - co * 3584;
    int ci = rem / 7;
    int k = rem - ci * 7;
    o[(((size_t)k * 32 + (ci >> 4)) * 512 + co) * 16 + (ci & 15)] = (int8_t)t;
  }
}

// ---------------- per-token activation quant for x; packed q layout [b][kq32][LinH][16] ----------------
__global__ void act_quant_kernel(const float* __restrict__ x, int8_t* __restrict__ qd,
                                 float* __restrict__ inv, int Lb, int lbsh, int LinH) {
  int tok = blockIdx.x;
  int b = tok >> lbsh;
  int t = tok & (Lb - 1);
  const float* row = x + (size_t)tok * C_;
  int tid = threadIdx.x;
  float v0 = row[tid];
  float v1 = row[tid + 256];
  float m = fmaxf(fabsf(v0), fabsf(v1));
  #pragma unroll
  for (int off = 32; off > 0; off >>= 1) m = fmaxf(m, __shfl_down(m, off, 64));
  __shared__ float s[4];
  __shared__ __align__(16) int8_t sq[512];
  if ((tid & 63) == 0) s[tid >> 6] = m;
  __syncthreads();
  m = fmaxf(fmaxf(s[0], s[1]), fmaxf(s[2], s[3]));
  float scale = 127.0f / fmaxf(m, 1e-5f);
  float q0 = fminf(fmaxf(rintf(v0 * scale), -128.f), 127.f);
  float q1 = fminf(fmaxf(rintf(v1 * scale), -128.f), 127.f);
  sq[tid] = (int8_t)q0;
  sq[tid + 256] = (int8_t)q1;
  __syncthreads();
  if (tid < 32)
    *(v4i*)(qd + ((size_t)(b * 32 + tid) * LinH + 8 + t) * 16) = *(const v4i*)(sq + tid * 16);
  if (tid == 0) inv[(size_t)b * LinH + 8 + t] = 1.0f / scale;
}

// ---------------- fused MFMA conv ----------------
// Block 1024 thr (16 waves). Block tile 32M x 512N (ALL channels); wave w owns cols
// [w*32, w*32+32): ONE acc + ONE fs (32 VGPR state -> no spill, deep B pipelining).
// A staged once in LDS; B per-lane global->reg, linear stride. 4 waves/SIMD.
// EPI: 0 = write h f32 + quant(qout,invout)    (convT)
//      1 = silu + quant(qout,invout), no f32    (conv7#1)
//      2 = +res, deterministic LayerNorm -> ln  (conv7#2)
template<int NTAPS, bool CONVT, int EPI>
__global__ __launch_bounds__(1024, 4)
void conv_fused(const int8_t* __restrict__ qin, const float* __restrict__ invp, int LinH,
                const int8_t* __restrict__ wq, const float* __restrict__ wsum, int widx,
                float wninv, const float* __restrict__ bias,
                float* __restrict__ hout,
                int8_t* __restrict__ qout, float* __restrict__ invout, int LoutH,
                const float* __restrict__ res, const float* __restrict__ g,
                const float* __restrict__ be, float* __restrict__ lnout, int Lout) {
  __shared__ __align__(16) int8_t sA[32 * 38 * 16];      // 19456 B
  __shared__ float sInv[40];
  __shared__ float sRedA[16][32];
  __shared__ float sRedB[16][32];
  __shared__ float sS0[32];
  __shared__ float sS1[32];
  __shared__ __align__(16) int8_t sQ[32][512];           // EPI 0/1 only

  const int tid = threadIdx.x;
  const int w = tid >> 6, lane = tid & 63, q = lane >> 5, l31 = lane & 31;
  const int t0 = blockIdx.x * 32;
  const int b = blockIdx.y;
  int s0 = -3;
  const int8_t* wq_p = wq;
  int parity = 0;
  if (CONVT) {
    parity = blockIdx.z;
    s0 = parity - 1;
    wq_p += (size_t)parity * 2 * 32 * 512 * 16;
  }
  const int8_t* qin_b = qin + (size_t)b * 32 * LinH * 16;
  const float* inv_b = invp + (size_t)b * LinH + 8;

  // ---- prologue: stage A (32 kq x 38 rows = 1216 16B units) + sInv, one barrier
  #pragma unroll
  for (int i = 0; i < 2; ++i) {
    int base = i * 1024 + w * 64;      // wave-uniform
    if (base < 1216) {
      int u = base + lane;
      int kq = u / 38;
      int row = u - kq * 38;
      gl16(qin_b + ((size_t)kq * LinH + (size_t)(t0 + 5 + row)) * 16,
           sA + (size_t)base * 16);
    }
  }
  if (tid < 38) sInv[tid] = inv_b[t0 - 3 + tid];
  __syncthreads();   // drains gl16 (vmcnt) + sInv write; the ONLY main-path barrier

  float fs[16];
  v16i acc{};
  #pragma unroll
  for (int r = 0; r < 16; ++r) { fs[r] = 0.f; acc[r] = 0; }

  const int col0 = w * 32 + l31;
  const int8_t* wt_base = wq_p + ((size_t)q * 512 + (size_t)col0) * 16;

  #pragma unroll 1
  for (int tap = 0; tap < NTAPS; ++tap) {
    const int shift = s0 + tap;
    const int8_t* aP = sA + (((size_t)q * 38) + (size_t)(3 + shift + l31)) * 16;
    const int8_t* wt = wt_base + (size_t)tap * (32 * 512 * 16);
    #pragma unroll
    for (int ks = 0; ks < 16; ++ks) {
      v4i a  = *(const v4i*)(aP + (size_t)ks * (2 * 38 * 16));
      v4i bf = *(const v4i*)(wt + (size_t)ks * 16384);
      acc = __builtin_amdgcn_mfma_i32_32x32x32_i8(a, bf, acc, 0, 0, 0);
    }
    // end of tap: fold i32 -> fp32 with per-input-row scale
    #pragma unroll
    for (int r = 0; r < 16; ++r) {
      int ro = (r & 3) + 8 * (r >> 2) + 4 * q;
      float sc = sInv[3 + shift + ro];
      fs[r] = fmaf((float)acc[r], sc, fs[r]);
      acc[r] = 0;
    }
  }

  // ---- epilogue: bias/dequant, then fused consumer stage
  const float wdq = fmaxf(wsum[widx] * wninv, 1e-5f);
  const float bv = bias[col0];
  #pragma unroll
  for (int r = 0; r < 16; ++r) fs[r] = fs[r] * wdq + bv;

  if constexpr (EPI == 0) {
    // write h f32 (token = 2*(t0+ro)+parity)
    #pragma unroll
    for (int r = 0; r < 16; ++r) {
      int ro = (r & 3) + 8 * (r >> 2) + 4 * q;
      size_t base = ((size_t)b * Lout + 2 * (size_t)(t0 + ro) + parity) * 512;
      hout[base + col0] = fs[r];
    }
  }
  if constexpr (EPI == 1) {
    #pragma unroll
    for (int r = 0; r < 16; ++r) fs[r] = fs[r] / (1.0f + expf(-fs[r]));
  }

  if constexpr (EPI <= 1) {
    // ---- per-token absmax (deterministic: shuffle tree + fixed 16-wave fold)
    #pragma unroll
    for (int r = 0; r < 16; ++r) {
      int ro = (r & 3) + 8 * (r >> 2) + 4 * q;
      float m = fabsf(fs[r]);
      #pragma unroll
      for (int off = 16; off > 0; off >>= 1) m = fmaxf(m, __shfl_xor(m, off, 64));
      if (l31 == 0) sRedA[w][ro] = m;
    }
    __syncthreads();
    if (tid < 32) {
      float m = sRedA[0][tid];
      #pragma unroll
      for (int ww = 1; ww < 16; ++ww) m = fmaxf(m, sRedA[ww][tid]);
      float mm = fmaxf(m, 1e-5f);
      sS0[tid] = 127.0f / mm;
      int tok = CONVT ? (2 * (t0 + tid) + parity) : (t0 + tid);
      invout[(size_t)b * LoutH + 8 + tok] = mm * (1.0f / 127.0f);
    }
    __syncthreads();
    #pragma unroll
    for (int r = 0; r < 16; ++r) {
      int ro = (r & 3) + 8 * (r >> 2) + 4 * q;
      float sc = sS0[ro];
      float qv = fminf(fmaxf(rintf(fs[r] * sc), -128.f), 127.f);
      sQ[ro][col0] = (int8_t)qv;
    }
    __syncthreads();
    {
      int u = tid;                      // 0..1023: (row, 16B-unit)
      int row = u >> 5, unit = u & 31;
      int tok = CONVT ? (2 * (t0 + row) + parity) : (t0 + row);
      *(v4i*)(qout + (((size_t)b * 32 + unit) * LoutH + 8 + tok) * 16) =
          *(const v4i*)(&sQ[row][unit * 16]);
    }
  } else {
    // ---- EPI 2: residual + deterministic two-pass LayerNorm
    #pragma unroll
    for (int r = 0; r < 16; ++r) {
      int ro = (r & 3) + 8 * (r >> 2) + 4 * q;
      size_t base = ((size_t)b * Lout + (size_t)(t0 + ro)) * 512;
      fs[r] += res[base + col0];
    }
    // pass 1: mean
    #pragma unroll
    for (int r = 0; r < 16; ++r) {
      int ro = (r & 3) + 8 * (r >> 2) + 4 * q;
      float s = fs[r];
      #pragma unroll
      for (int off = 16; off > 0; off >>= 1) s += __shfl_xor(s, off, 64);
      if (l31 == 0) sRedA[w][ro] = s;
    }
    __syncthreads();
    if (tid < 32) {
      float s = sRedA[0][tid];
      #pragma unroll
      for (int ww = 1; ww < 16; ++ww) s += sRedA[ww][tid];
      sS0[tid] = s * (1.0f / 512.0f);
    }
    __syncthreads();
    // pass 2: variance around mean
    #pragma unroll
    for (int r = 0; r < 16; ++r) {
      int ro = (r & 3) + 8 * (r >> 2) + 4 * q;
      float mu = sS0[ro];
      float d = fs[r] - mu;
      float ss = d * d;
      #pragma unroll
      for (int off = 16; off > 0; off >>= 1) ss += __shfl_xor(ss, off, 64);
      if (l31 == 0) sRedB[w][ro] = ss;
    }
    __syncthreads();
    if (tid < 32) {
      float ssum = sRedB[0][tid];
      #pragma unroll
      for (int ww = 1; ww < 16; ++ww) ssum += sRedB[ww][tid];
      float var = ssum * (1.0f / 512.0f);
      sS1[tid] = 1.0f / sqrtf(var + 1e-5f);
    }
    __syncthreads();
    const float gv = g[col0];
    const float ev = be[col0];
    #pragma unroll
    for (int r = 0; r < 16; ++r) {
      int ro = (r & 3) + 8 * (r >> 2) + 4 * q;
      float mu = sS0[ro], rs = sS1[ro];
      size_t base = ((size_t)b * Lout + (size_t)(t0 + ro)) * 512;
      lnout[base + col0] = (fs[r] - mu) * rs * gv + ev;
    }
  }
}

// ---------------- launch ----------------

extern "C" void kernel_launch(void* const* d_in, const int* in_sizes, int n_in,
                              void* d_out, int out_size, void* d_ws, size_t ws_size,
                              hipStream_t stream) {
  const float* x    = (const float*)d_in[0];
  const float* w_up = (const float*)d_in[1];
  const float* b_up = (const float*)d_in[2];
  const float* w_r1 = (const float*)d_in[3];
  const float* b_r1 = (const float*)d_in[4];
  const float* w_r2 = (const float*)d_in[5];
  const float* b_r2 = (const float*)d_in[6];
  const float* ln_w = (const float*)d_in[7];
  const float* ln_b = (const float*)d_in[8];
  float* out = (float*)d_out;

  const int LXH = T_ + 16;   // 2064 rows per batch (halo 8 each side)
  const int LHH = L_ + 16;   // 4112

  char* ws = (char*)d_ws;
  size_t off = 0;
  auto alloc = [&](size_t sz) { size_t p = off; off += (sz + 255) & ~(size_t)255; return p; };
  // zero region: wsum + q buffers + inv buffers (halo rows/scales must be 0)
  float*  wsum  = (float*) (ws + alloc(256));
  int8_t* qx    = (int8_t*)(ws + alloc((size_t)B_ * 32 * LXH * 16));   // 2.1 MB
  int8_t* qh    = (int8_t*)(ws + alloc((size_t)B_ * 32 * LHH * 16));   // 4.2 MB
  int8_t* qh2   = (int8_t*)(ws + alloc((size_t)B_ * 32 * LHH * 16));   // 4.2 MB
  float*  invx  = (float*) (ws + alloc((size_t)B_ * LXH * 4));
  float*  invh  = (float*) (ws + alloc((size_t)B_ * LHH * 4));
  float*  invh2 = (float*) (ws + alloc((size_t)B_ * LHH * 4));
  size_t zero_bytes = off;
  float*  partial = (float*)(ws + alloc(3 * 256 * 4));                 // det. reduction slots
  int8_t* wqup = (int8_t*)(ws + alloc((size_t)4 * 32 * 512 * 16));     // 1 MB
  int8_t* wq1  = (int8_t*)(ws + alloc((size_t)7 * 32 * 512 * 16));     // 1.8 MB
  int8_t* wq2  = (int8_t*)(ws + alloc((size_t)7 * 32 * 512 * 16));     // 1.8 MB
  float*  h    = (float*) (ws + alloc((size_t)B_ * L_ * C_ * 4));      // 16.8 MB

  hipMemsetAsync(ws, 0, zero_bytes, stream);  // wsum + q/inv halos

  abssum3_partial<<<dim3(256, 3), 256, 0, stream>>>(w_up, w_r1, w_r2, partial);
  abssum3_final<<<3, 256, 0, stream>>>(partial, wsum);
  tern_all_kernel<<<dim3(NR / 256, 3), 256, 0, stream>>>(w_up, w_r1, w_r2,
                                                         wqup, wq1, wq2, wsum);

  act_quant_kernel<<<B_ * T_, 256, 0, stream>>>(x, qx, invx, T_, 11, LXH);

  // convT + fused quant: grid (64 mtiles, B, parity) = 256 blocks of 16 waves
  conv_fused<2, true, 0><<<dim3(64, B_, 2), 1024, 0, stream>>>(
      qx, invx, LXH, wqup, wsum, 0, 1.0f / (float)NUP, b_up,
      h, qh, invh, LHH, nullptr, nullptr, nullptr, nullptr, L_);

  // conv7#1 + silu + fused quant (no f32 r buffer): grid (128, B) = 256 blocks
  conv_fused<7, false, 1><<<dim3(128, B_, 1), 1024, 0, stream>>>(
      qh, invh, LHH, wq1, wsum, 1, 1.0f / (float)NR, b_r1,
      nullptr, qh2, invh2, LHH, nullptr, nullptr, nullptr, nullptr, L_);

  // conv7#2 + residual + fused LayerNorm -> out: grid (128, B) = 256 blocks
  conv_fused<7, false, 2><<<dim3(128, B_, 1), 1024, 0, stream>>>(
      qh2, invh2, LHH, wq2, wsum, 2, 1.0f / (float)NR, b_r2,
      nullptr, nullptr, nullptr, 0, h, ln_w, ln_b, out, L_);
}